// Round 10
// baseline (526.035 us; speedup 1.0000x reference)
//
#include <hip/hip_runtime.h>
#include <math.h>

// ---------------------------------------------------------------------------
// Net_37512244363273: 5-level edge-conditioned graph conv + voxel pooling + FC
// Round 10: seg0 edge data was touched 4x (part0, bucket0, conv0, hstats).
// Now 2x: part0 computes h once, writes 32B records (x, h0x..h4x, key) AND
// accumulates level-0 h-stats in-kernel (hstats_k now covers only L1-4);
// conv0b (one block per 512-node bucket) streams records once, accumulates
// per-node sums + count via LDS atomics, finalizes y in-block. bucket0 /
// csr0 / rp0 deleted. Segs 1-9 keep the XCD-bucketed atomic CSR build.
// Top profile entry is now the harness's 268MB workspace re-poison (42 us,
// not ours). Output: 80 log_softmax + closs = 81 floats.
// ---------------------------------------------------------------------------

#define NBUCK 8
#define TILES0 256                 // 1048576 / 4096

// ---- segment descriptor for CSR builds (segs 1-9: edge 1-4 + cluster 0-4) --
struct SegArgs {
    const int* idx[10];
    int*       cnt[10];
    int*       rp [10];
    int*       out[10];
    int        n  [10];
    int        nb [10];
    int        shift[10];
    int        tstart[11];
};

struct ScanAux {
    int* tilesum;
    int* tileoff;
    int  sstart[11];
    int  T;
};

// XCD-bucketed histogram (per-element global atomics; small segs only).
__global__ __launch_bounds__(256) void hist_all_k(SegArgs a) {
    int B = blockIdx.x;
    int bucket = B % NBUCK;
    int T = B / NBUCK;
    int s = 0;
    while (s < 9 && T >= a.tstart[s + 1]) s++;
    int i = (T - a.tstart[s]) * 256 + threadIdx.x;
    if (i >= a.n[s]) return;
    int d = a.idx[s][i];
    if ((d >> a.shift[s]) != bucket) return;
    atomicAdd(&a.cnt[s][d], 1);
}

// 3-phase hierarchical scan over segs 1-9 cnt arrays.
__global__ __launch_bounds__(256) void scanA_k(SegArgs a, ScanAux x) {
    int b = blockIdx.x;
    int s = 0;
    while (s < 9 && b >= x.sstart[s + 1]) s++;
    int tloc = b - x.sstart[s];
    int nb = a.nb[s];
    const int* cnt = a.cnt[s];
    int i0 = tloc * 4096 + threadIdx.x * 16;
    int sum = 0;
    #pragma unroll
    for (int k = 0; k < 16; k++) {
        int i = i0 + k;
        if (i < nb) sum += cnt[i];
    }
    #pragma unroll
    for (int o = 32; o; o >>= 1) sum += __shfl_down(sum, o);
    __shared__ int red[4];
    if ((threadIdx.x & 63) == 0) red[threadIdx.x >> 6] = sum;
    __syncthreads();
    if (threadIdx.x == 0)
        x.tilesum[b] = red[0] + red[1] + red[2] + red[3];
}

__global__ __launch_bounds__(64) void scanB_k(SegArgs a, ScanAux x) {
    int lane = threadIdx.x;
    int orig = (lane < x.T) ? x.tilesum[lane] : 0;
    int val = orig;
    #pragma unroll
    for (int d = 1; d < 64; d <<= 1) {
        int v = __shfl_up(val, d);
        if (lane >= d) val += v;
    }
    int excl = val - orig;
    int s = 0;
    while (s < 9 && lane >= x.sstart[s + 1]) s++;
    int segExcl = __shfl(excl, x.sstart[s]);
    if (lane < x.T) {
        x.tileoff[lane] = excl - segExcl;
        if (lane == x.sstart[s + 1] - 1)
            a.rp[s][a.nb[s]] = val - segExcl;
    }
}

__global__ __launch_bounds__(256) void scanC_k(SegArgs a, ScanAux x) {
    int b = blockIdx.x;
    int s = 0;
    while (s < 9 && b >= x.sstart[s + 1]) s++;
    int tloc = b - x.sstart[s];
    int nb = a.nb[s];
    const int* cnt = a.cnt[s];
    int* rp = a.rp[s];
    int i0 = tloc * 4096 + threadIdx.x * 16;
    int v[16];
    int sum = 0;
    #pragma unroll
    for (int k = 0; k < 16; k++) {
        int i = i0 + k;
        v[k] = (i < nb) ? cnt[i] : 0;
        sum += v[k];
    }
    __shared__ int sc[256];
    int acc = sum;
    sc[threadIdx.x] = acc;
    __syncthreads();
    for (int d = 1; d < 256; d <<= 1) {
        int t2 = (threadIdx.x >= d) ? sc[threadIdx.x - d] : 0;
        __syncthreads();
        acc += t2;
        sc[threadIdx.x] = acc;
        __syncthreads();
    }
    int running = x.tileoff[b] + (acc - sum);
    #pragma unroll
    for (int k = 0; k < 16; k++) {
        int i = i0 + k;
        if (i < nb) rp[i] = running;
        running += v[k];
    }
}

// XCD-bucketed countdown-scatter (small segs only).
__global__ __launch_bounds__(256) void scatter_all_k(SegArgs a) {
    int B = blockIdx.x;
    int bucket = B % NBUCK;
    int T = B / NBUCK;
    int s = 0;
    while (s < 9 && T >= a.tstart[s + 1]) s++;
    int i = (T - a.tstart[s]) * 256 + threadIdx.x;
    if (i >= a.n[s]) return;
    int d = a.idx[s][i];
    if ((d >> a.shift[s]) != bucket) return;
    int p = atomicSub(&a.cnt[s][d], 1) - 1;
    a.out[s][a.rp[s][d] + p] = i;
}

// ---------------------------------------------------------------------------
// Seg-0 pipeline: deterministic 128-bucket partition with fused h + stats,
// then per-bucket LDS accumulation. No per-node CSR, no global atomics in
// placement (only 20 stat atomics per part0 block).
// ---------------------------------------------------------------------------
__global__ __launch_bounds__(256) void cnt0_k(
    const int* __restrict__ dst, int* __restrict__ M)
{
    __shared__ int h[128];
    int t = threadIdx.x;
    if (t < 128) h[t] = 0;
    __syncthreads();
    int base = blockIdx.x * 4096 + t;
    #pragma unroll
    for (int it = 0; it < 16; it++)
        atomicAdd(&h[dst[base + it * 256] >> 9], 1);      // LDS
    __syncthreads();
    if (t < 128) M[blockIdx.x * 128 + t] = h[t];
}

// per-bucket exclusive scan over the 256 tiles.
__global__ __launch_bounds__(256) void colscan_k(
    const int* __restrict__ M, int* __restrict__ M2, int* __restrict__ colTotal)
{
    int b = blockIdx.x, t = threadIdx.x;
    int v = M[t * 128 + b];
    __shared__ int sc[256];
    sc[t] = v;
    __syncthreads();
    for (int d = 1; d < 256; d <<= 1) {
        int u = (t >= d) ? sc[t - d] : 0;
        __syncthreads();
        sc[t] += u;
        __syncthreads();
    }
    M2[t * 128 + b] = sc[t] - v;
    if (t == 255) colTotal[b] = sc[255];
}

__global__ __launch_bounds__(128) void bktscan_k(
    const int* __restrict__ colTotal, int* __restrict__ bucketStart)
{
    int t = threadIdx.x;
    int v = colTotal[t];
    __shared__ int sc[128];
    sc[t] = v;
    __syncthreads();
    for (int d = 1; d < 128; d <<= 1) {
        int u = (t >= d) ? sc[t - d] : 0;
        __syncthreads();
        sc[t] += u;
        __syncthreads();
    }
    bucketStart[t] = sc[t] - v;
    if (t == 127) bucketStart[128] = sc[127];
}

// partition + fused h/tanh + level-0 h-stats. Record (2 x float4):
//   A = (x_src, h0*x, h1*x, h2*x), B = (h3*x, h4*x, key_as_float_bits, 0).
__global__ __launch_bounds__(256) void part0_k(
    const int* __restrict__ src, const int* __restrict__ dst,
    const float* __restrict__ ea, const float* __restrict__ x0,
    const int* __restrict__ M2, const int* __restrict__ bucketStart,
    float4* __restrict__ pay2,
    const float* __restrict__ w1, const float* __restrict__ b1,
    float* __restrict__ H0)
{
    __shared__ int cur[128];
    __shared__ float w1s[15], b1s[5];
    __shared__ float red[4][20];
    int t = threadIdx.x;
    if (t < 128) cur[t] = bucketStart[t] + M2[blockIdx.x * 128 + t];
    if (t >= 128 && t < 143) w1s[t - 128] = w1[t - 128];
    if (t >= 160 && t < 165) b1s[t - 160] = b1[t - 160];
    __syncthreads();

    float acc[20];
    #pragma unroll
    for (int i = 0; i < 20; i++) acc[i] = 0.f;

    int base = blockIdx.x * 4096 + t;
    #pragma unroll 4
    for (int it = 0; it < 16; it++) {
        int i = base + it * 256;
        int d = dst[i];
        float e0 = ea[i * 3], e1 = ea[i * 3 + 1], e2 = ea[i * 3 + 2];
        float h[5];
        #pragma unroll
        for (int k = 0; k < 5; k++)
            h[k] = tanhf(e0 * w1s[k] + e1 * w1s[5 + k] + e2 * w1s[10 + k] + b1s[k]);
        int p = 5;
        #pragma unroll
        for (int k = 0; k < 5; k++) {
            acc[k] += h[k];
            #pragma unroll
            for (int k2 = k; k2 < 5; k2++) acc[p++] += h[k] * h[k2];
        }
        float xv = x0[src[i]];
        int ps = atomicAdd(&cur[d >> 9], 1);              // LDS
        pay2[2 * ps]     = make_float4(xv, h[0] * xv, h[1] * xv, h[2] * xv);
        pay2[2 * ps + 1] = make_float4(h[3] * xv, h[4] * xv, __int_as_float(d), 0.f);
    }

    // level-0 h-stat reduction: wave shfl -> LDS -> 20 atomics per block
    int wid = t >> 6, lane = t & 63;
    #pragma unroll
    for (int v = 0; v < 20; v++) {
        float s = acc[v];
        #pragma unroll
        for (int o = 32; o; o >>= 1) s += __shfl_down(s, o);
        if (lane == 0) red[wid][v] = s;
    }
    __syncthreads();
    if (t < 20)
        atomicAdd(&H0[t], red[0][t] + red[1][t] + red[2][t] + red[3][t]);
}

// conv0b: one block per 512-node bucket. Streams the bucket's records once,
// LDS-accumulates per-node (Sx, Sh*x.., cnt), finalizes y in-block.
__global__ __launch_bounds__(1024) void conv0b_k(
    const float4* __restrict__ pay2, const int* __restrict__ bucketStart,
    const float* __restrict__ w2, const float* __restrict__ b2,
    const float* __restrict__ root, const float* __restrict__ bias,
    const float* __restrict__ x, float* __restrict__ y)
{
    __shared__ float S[512 * 8];           // [node][0..5]=sums, [6]=cnt
    __shared__ float w2s[60], b2s[12], roots[12], biass[12];
    int t = threadIdx.x;
    if (t < 60) w2s[t] = w2[t];
    else if (t >= 64  && t < 76)  b2s[t - 64]    = b2[t - 64];
    else if (t >= 128 && t < 140) roots[t - 128] = root[t - 128];
    else if (t >= 192 && t < 204) biass[t - 192] = bias[t - 192];
    for (int u = t; u < 512 * 8; u += 1024) S[u] = 0.f;
    __syncthreads();

    int b = blockIdx.x;
    int lo = bucketStart[b], hi = bucketStart[b + 1];
    int bin0 = b << 9;
    for (int j = lo + t; j < hi; j += 1024) {
        float4 A = pay2[2 * j], B = pay2[2 * j + 1];
        int rel = __float_as_int(B.z) - bin0;
        float* Sp = &S[rel * 8];
        atomicAdd(&Sp[0], A.x);
        atomicAdd(&Sp[1], A.y);
        atomicAdd(&Sp[2], A.z);
        atomicAdd(&Sp[3], A.w);
        atomicAdd(&Sp[4], B.x);
        atomicAdd(&Sp[5], B.y);
        atomicAdd(&Sp[6], 1.f);
    }
    __syncthreads();

    if (t < 512) {
        int v = bin0 + t;
        float* Sp = &S[t * 8];
        float inv = 1.f / fmaxf(Sp[6], 1.f);
        float xv = x[v];
        #pragma unroll
        for (int o = 0; o < 12; o++) {
            float msg = b2s[o] * Sp[0] + w2s[o] * Sp[1] + w2s[12 + o] * Sp[2] +
                        w2s[24 + o] * Sp[3] + w2s[36 + o] * Sp[4] + w2s[48 + o] * Sp[5];
            y[v * 12 + o] = msg * inv + xv * roots[o] + biass[o];
        }
    }
}

// ---------------------------------------------------------------------------
// hstats (levels 1-4 only now) / wstats: closs via h-statistics.
// ---------------------------------------------------------------------------
struct HArgs {
    const float* eattr[5];
    const float* w1[5];
    const float* b1[5];
    float*       H;
    int          E[5];
    int          bstart[6];
};

__global__ __launch_bounds__(256) void hstats_k(HArgs a) {
    const int K = 32;
    int b = blockIdx.x, l = 0;
    while (l < 4 && b >= a.bstart[l + 1]) l++;
    int bloc = b - a.bstart[l];
    const float* ea = a.eattr[l];
    float w1r[15], b1r[5];
    #pragma unroll
    for (int i = 0; i < 15; i++) w1r[i] = a.w1[l][i];
    #pragma unroll
    for (int i = 0; i < 5; i++)  b1r[i] = a.b1[l][i];
    float acc[20];
    #pragma unroll
    for (int i = 0; i < 20; i++) acc[i] = 0.f;
    int base = bloc * 256 * K + threadIdx.x;
    for (int it = 0; it < K; it++) {
        int e = base + it * 256;
        if (e < a.E[l]) {
            float e0 = ea[e * 3], e1 = ea[e * 3 + 1], e2 = ea[e * 3 + 2];
            float h[5];
            #pragma unroll
            for (int k = 0; k < 5; k++)
                h[k] = tanhf(e0 * w1r[k] + e1 * w1r[5 + k] + e2 * w1r[10 + k] + b1r[k]);
            int p = 5;
            #pragma unroll
            for (int k = 0; k < 5; k++) {
                acc[k] += h[k];
                #pragma unroll
                for (int k2 = k; k2 < 5; k2++) acc[p++] += h[k] * h[k2];
            }
        }
    }
    __shared__ float red[4][20];
    int wid = threadIdx.x >> 6, lane = threadIdx.x & 63;
    #pragma unroll
    for (int v = 0; v < 20; v++) {
        float s = acc[v];
        #pragma unroll
        for (int off = 32; off; off >>= 1) s += __shfl_down(s, off);
        if (lane == 0) red[wid][v] = s;
    }
    __syncthreads();
    if (threadIdx.x < 20) {
        float s = red[0][threadIdx.x] + red[1][threadIdx.x] +
                  red[2][threadIdx.x] + red[3][threadIdx.x];
        atomicAdd(&a.H[l * 20 + threadIdx.x], s);
    }
}

struct WArgs {
    const float* w2[5];
    const float* b2[5];
    const float* H;
    float*       sq;
    int          cico[5];
    int          E[5];
};

__global__ __launch_bounds__(64) void wstats_k(WArgs a) {
    int l = blockIdx.x;
    const float* w2 = a.w2[l];
    const float* b2 = a.b2[l];
    int cico = a.cico[l];
    float d[21];
    #pragma unroll
    for (int i = 0; i < 21; i++) d[i] = 0.f;
    for (int u = threadIdx.x; u < cico; u += 64) {
        float b = b2[u];
        float w[5];
        #pragma unroll
        for (int k = 0; k < 5; k++) w[k] = w2[k * cico + u];
        int p = 0;
        #pragma unroll
        for (int k = 0; k < 5; k++) {
            #pragma unroll
            for (int k2 = k; k2 < 5; k2++) d[p++] += w[k] * w[k2];
        }
        #pragma unroll
        for (int k = 0; k < 5; k++) d[15 + k] += b * w[k];
        d[20] += b * b;
    }
    #pragma unroll
    for (int i = 0; i < 21; i++) {
        #pragma unroll
        for (int off = 32; off; off >>= 1) d[i] += __shfl_down(d[i], off);
    }
    if (threadIdx.x == 0) {
        const float* H1 = a.H + l * 20;
        const float* H2 = H1 + 5;
        float sq = (float)a.E[l] * d[20];
        #pragma unroll
        for (int k = 0; k < 5; k++) sq += 2.f * d[15 + k] * H1[k];
        int p = 0;
        #pragma unroll
        for (int k = 0; k < 5; k++) {
            #pragma unroll
            for (int k2 = k; k2 < 5; k2++) {
                sq += ((k == k2) ? 1.f : 2.f) * d[p] * H2[p];
                p++;
            }
        }
        a.sq[l] = sq;
    }
}

// ---------------------------------------------------------------------------
// coop_conv_k (L1-L4): one block per node (unchanged).
// ---------------------------------------------------------------------------
template<int CI, int CO>
__global__ __launch_bounds__(256) void coop_conv_k(
    const int* __restrict__ rp, const int* __restrict__ eid,
    const int* __restrict__ src, const float* __restrict__ eattr,
    const float* __restrict__ w1, const float* __restrict__ b1,
    const float* __restrict__ w2, const float* __restrict__ b2,
    const float* __restrict__ root, const float* __restrict__ bias,
    const float* __restrict__ x, float* __restrict__ y)
{
    constexpr int CH   = 48;
    constexpr int CICO = CI * CO;
    static_assert(6 * CI <= 256, "phase-A lanes");
    __shared__ float w1s[20];
    __shared__ int   eb[CH], svb[CH];
    __shared__ float hb[CH * 6];
    __shared__ float xs[CH * CI];
    __shared__ float S[6 * CI];

    int t = threadIdx.x;
    int v = blockIdx.x;
    if (t < 20) w1s[t] = (t < 15) ? w1[t] : b1[t - 15];
    int r0 = rp[v], r1 = rp[v + 1];
    int d  = r1 - r0;
    float acc = 0.f;

    for (int c0 = r0; c0 < r1; c0 += CH) {
        int cn = min(CH, r1 - c0);
        if (t < cn) {
            int e = eid[c0 + t];
            eb[t]  = e;
            svb[t] = src[e];
            hb[t * 6] = 1.f;
        }
        __syncthreads();
        if (t < cn * 5) {
            int j = t / 5, k = t % 5;
            int e = eb[j];
            float e0 = eattr[e * 3], e1 = eattr[e * 3 + 1], e2 = eattr[e * 3 + 2];
            hb[j * 6 + 1 + k] =
                tanhf(e0 * w1s[k] + e1 * w1s[5 + k] + e2 * w1s[10 + k] + w1s[15 + k]);
        }
        for (int u = t; u < cn * CI; u += 256)
            xs[u] = x[(size_t)svb[u / CI] * CI + (u % CI)];
        __syncthreads();
        if (t < 6 * CI) {
            int i = t / 6, k6 = t % 6;
            for (int j = 0; j < cn; j++)
                acc += hb[j * 6 + k6] * xs[j * CI + i];
        }
        __syncthreads();
    }

    if (t < 6 * CI) S[t] = acc;
    __syncthreads();

    if (t < CO) {
        float m = 0.f;
        for (int i = 0; i < CI; i++) {
            m += b2[i * CO + t] * S[i * 6];
            #pragma unroll
            for (int k = 0; k < 5; k++)
                m += w2[k * CICO + i * CO + t] * S[i * 6 + 1 + k];
        }
        m /= fmaxf((float)d, 1.f);
        for (int i = 0; i < CI; i++)
            m += x[(size_t)v * CI + i] * root[i * CO + t];
        y[(size_t)v * CO + t] = m + bias[t];
    }
}

// ---------------------------------------------------------------------------
// pool_k (unchanged).
// ---------------------------------------------------------------------------
template<int CO>
__global__ __launch_bounds__(256) void pool_k(
    int NN,
    const int* __restrict__ crp, const int* __restrict__ cnid,
    const float* __restrict__ y, const float* __restrict__ pos,
    float* __restrict__ xn, float* __restrict__ pn)
{
    int t = blockIdx.x * 256 + threadIdx.x;
    if (t >= NN * (CO + 3)) return;
    int c = t / (CO + 3), o = t % (CO + 3);
    int r0 = crp[c], r1 = crp[c + 1];
    int d = r1 - r0;
    if (o < CO) {
        float m = -INFINITY;
        for (int j = r0; j < r1; j++)
            m = fmaxf(m, y[(size_t)cnid[j] * CO + o]);
        if (d == 0 || !isfinite(m)) m = 0.f;
        xn[c * (CO + 3) + o] = m;
    } else {
        int k = o - CO;
        float sum = 0.f;
        for (int j = r0; j < r1; j++)
            sum += pos[cnid[j] * 3 + k];
        float pm = sum / fmaxf((float)d, 1.f);
        xn[c * (CO + 3) + CO + k] = pm;
        pn[c * 3 + k] = pm;
    }
}

// ---------------------------------------------------------------------------
// fc_k (unchanged).
// ---------------------------------------------------------------------------
__global__ __launch_bounds__(128) void fc_k(
    const float* __restrict__ x5,
    const float* __restrict__ fc_w, const float* __restrict__ fc_b,
    const float* __restrict__ sq, float* __restrict__ out)
{
    __shared__ float feat[8 * 376];
    __shared__ float logit[80];
    __shared__ float roff[8];
    for (int t = threadIdx.x; t < 8 * 376; t += 128) feat[t] = x5[t];
    __syncthreads();
    int t = threadIdx.x;
    if (t < 80) {
        int b = t / 10, j = t % 10;
        float acc = fc_b[j];
        for (int k = 0; k < 376; k++) acc += feat[b * 376 + k] * fc_w[k * 10 + j];
        logit[t] = acc;
    }
    __syncthreads();
    if (t < 8) {
        float m = -1e30f;
        for (int j = 0; j < 10; j++) m = fmaxf(m, logit[t * 10 + j]);
        float ssum = 0.f;
        for (int j = 0; j < 10; j++) ssum += expf(logit[t * 10 + j] - m);
        roff[t] = m + logf(ssum);
    }
    __syncthreads();
    if (t < 80) out[t] = logit[t] - roff[t / 10];
    if (t == 0) {
        float closs = 0.f;
        closs += sq[0] * (1.0f / 12582912.0f);
        closs += sq[1] * (1.0f / 78643200.0f);
        closs += sq[2] * (1.0f / 42205184.0f);
        closs += sq[3] * (1.0f / 18284544.0f);
        closs += sq[4] * (1.0f / 7028736.0f);
        out[80] = closs;
    }
}

// ---------------------------------------------------------------------------

extern "C" void kernel_launch(void* const* d_in, const int* in_sizes, int n_in,
                              void* d_out, int out_size, void* d_ws, size_t ws_size,
                              hipStream_t stream)
{
    static const int NSa[6] = {65536, 16384, 4096, 1024, 256, 64};
    static const int ESa[5] = {1048576, 262144, 65536, 16384, 4096};
    static const int COa[5] = {12, 20, 28, 36, 44};
    static const int CIa[5] = {1, 15, 23, 31, 39};

    const float* x0   = (const float*)d_in[0];
    const float* pos0 = (const float*)d_in[1];

    // ---- workspace layout (words), ~40 MB total ----
    int* wsw = (int*)d_ws;
    size_t off = 0;
    auto alw = [&](size_t n) -> size_t {
        size_t p = off; off += (n + 63) & ~(size_t)63; return p;
    };
    size_t degO[5], cdegO[5];
    for (int l = 1; l < 5; l++) degO[l]  = alw(NSa[l]);
    for (int l = 0; l < 5; l++) cdegO[l] = alw(NSa[l + 1]);
    size_t HO = alw(100);
    size_t zeroWords = off;                               // zero-init to here
    size_t rpO[5], crpO[5], eidO[5], cnidO[5];
    for (int l = 1; l < 5; l++) rpO[l]  = alw(NSa[l] + 1);
    for (int l = 0; l < 5; l++) crpO[l] = alw(NSa[l + 1] + 1);
    for (int l = 1; l < 5; l++) eidO[l] = alw(ESa[l]);
    for (int l = 0; l < 5; l++) cnidO[l] = alw(NSa[l]);
    size_t tsO  = alw(64);
    size_t toO  = alw(64);
    size_t MO   = alw((size_t)TILES0 * 128);
    size_t M2O  = alw((size_t)TILES0 * 128);
    size_t ctO  = alw(128);
    size_t bsO  = alw(129);
    size_t payO = alw((size_t)ESa[0] * 8);                // 32B records
    size_t yO   = alw((size_t)65536 * 12);
    size_t sqO  = alw(8);
    size_t xnO[5], pnO[5];
    for (int l = 0; l < 5; l++) xnO[l] = alw((size_t)NSa[l + 1] * (COa[l] + 3));
    for (int l = 0; l < 5; l++) pnO[l] = alw((size_t)NSa[l + 1] * 3);

    hipMemsetAsync(d_ws, 0, zeroWords * 4, stream);

    // ---- segs 1-9 descriptor (edge segs 1-4 + cluster segs 0-4) ----
    SegArgs sa{};
    int nseg = 0;
    for (int l = 1; l < 5; l++) {
        sa.idx[nseg] = (const int*)d_in[3 + 10 * l];
        sa.cnt[nseg] = wsw + degO[l];
        sa.rp [nseg] = wsw + rpO[l];
        sa.out[nseg] = wsw + eidO[l];
        sa.n  [nseg] = ESa[l];
        sa.nb [nseg] = NSa[l];
        nseg++;
    }
    for (int l = 0; l < 5; l++) {
        sa.idx[nseg] = (const int*)d_in[5 + 10 * l];
        sa.cnt[nseg] = wsw + cdegO[l];
        sa.rp [nseg] = wsw + crpO[l];
        sa.out[nseg] = wsw + cnidO[l];
        sa.n  [nseg] = NSa[l];
        sa.nb [nseg] = NSa[l + 1];
        nseg++;
    }
    ScanAux sx{};
    int tiles = 0, btiles = 0;
    for (int s = 0; s < nseg; s++) {
        int lg = 31 - __builtin_clz(sa.nb[s]);
        sa.shift[s] = lg - 3;
        sa.tstart[s] = tiles;
        tiles += (sa.n[s] + 255) / 256;
        sx.sstart[s] = btiles;
        btiles += (sa.nb[s] + 4095) / 4096;
    }
    for (int s = nseg; s <= 10; s++) {
        sa.tstart[s] = tiles;
        sx.sstart[s] = btiles;
        if (s < 10) {
            sa.idx[s] = sa.idx[nseg - 1]; sa.cnt[s] = sa.cnt[nseg - 1];
            sa.rp[s] = sa.rp[nseg - 1];   sa.out[s] = sa.out[nseg - 1];
            sa.n[s] = 0; sa.nb[s] = 8; sa.shift[s] = 0;
        }
    }
    sx.T = btiles;
    sx.tilesum = wsw + tsO;
    sx.tileoff = wsw + toO;

    float4* pay2 = (float4*)(wsw + payO);
    float*  Hp   = (float*)(wsw + HO);

    // ---- seg0 deterministic radix build + fused h/stats ----
    cnt0_k   <<<TILES0, 256, 0, stream>>>((const int*)d_in[3], wsw + MO);
    colscan_k<<<128, 256, 0, stream>>>(wsw + MO, wsw + M2O, wsw + ctO);
    bktscan_k<<<1, 128, 0, stream>>>(wsw + ctO, wsw + bsO);
    part0_k  <<<TILES0, 256, 0, stream>>>(
        (const int*)d_in[2], (const int*)d_in[3], (const float*)d_in[4],
        x0, wsw + M2O, wsw + bsO, pay2,
        (const float*)d_in[6], (const float*)d_in[7], Hp);

    // ---- segs 1-9 atomic build ----
    hist_all_k   <<<tiles * NBUCK, 256, 0, stream>>>(sa);
    scanA_k      <<<btiles, 256, 0, stream>>>(sa, sx);
    scanB_k      <<<1, 64, 0, stream>>>(sa, sx);
    scanC_k      <<<btiles, 256, 0, stream>>>(sa, sx);
    scatter_all_k<<<tiles * NBUCK, 256, 0, stream>>>(sa);

    // ---- closs statistics: hstats for levels 1-4 only ----
    HArgs ha{};
    int bs = 0;
    ha.bstart[0] = 0;
    ha.eattr[0] = (const float*)d_in[4];
    ha.w1[0] = (const float*)d_in[6];
    ha.b1[0] = (const float*)d_in[7];
    ha.E[0] = 0;
    for (int l = 1; l < 5; l++) {
        ha.eattr[l] = (const float*)d_in[4 + 10 * l];
        ha.w1[l]    = (const float*)d_in[6 + 10 * l];
        ha.b1[l]    = (const float*)d_in[7 + 10 * l];
        ha.E[l]     = ESa[l];
        ha.bstart[l] = bs;
        bs += (ESa[l] + 256 * 32 - 1) / (256 * 32);
    }
    ha.bstart[5] = bs;
    ha.H = Hp;
    hstats_k<<<bs, 256, 0, stream>>>(ha);

    WArgs wa{};
    for (int l = 0; l < 5; l++) {
        wa.w2[l]   = (const float*)d_in[8 + 10 * l];
        wa.b2[l]   = (const float*)d_in[9 + 10 * l];
        wa.cico[l] = CIa[l] * COa[l];
        wa.E[l]    = ESa[l];
    }
    wa.H  = Hp;
    wa.sq = (float*)(wsw + sqO);
    wstats_k<<<5, 64, 0, stream>>>(wa);

    float* yb = (float*)(wsw + yO);

    // ---- level 0: per-bucket LDS accumulation conv ----
    conv0b_k<<<128, 1024, 0, stream>>>(
        pay2, wsw + bsO,
        (const float*)d_in[8], (const float*)d_in[9],
        (const float*)d_in[10], (const float*)d_in[11], x0, yb);
    pool_k<12><<<(NSa[1] * 15 + 255) / 256, 256, 0, stream>>>(
        NSa[1], wsw + crpO[0], wsw + cnidO[0], yb, pos0,
        (float*)(wsw + xnO[0]), (float*)(wsw + pnO[0]));

    // ---- levels 1-4 ----
#define LVLC(l, CI_, CO_) do {                                                 \
    const float* xin   = (const float*)(wsw + xnO[(l) - 1]);                   \
    const float* posin = (const float*)(wsw + pnO[(l) - 1]);                   \
    int N = NSa[(l)], NN = NSa[(l) + 1];                                       \
    coop_conv_k<CI_, CO_><<<N, 256, 0, stream>>>(                              \
        wsw + rpO[(l)], wsw + eidO[(l)],                                       \
        (const int*)d_in[2 + 10 * (l)], (const float*)d_in[4 + 10 * (l)],      \
        (const float*)d_in[6 + 10 * (l)], (const float*)d_in[7 + 10 * (l)],    \
        (const float*)d_in[8 + 10 * (l)], (const float*)d_in[9 + 10 * (l)],    \
        (const float*)d_in[10 + 10 * (l)], (const float*)d_in[11 + 10 * (l)],  \
        xin, yb);                                                              \
    pool_k<CO_><<<(NN * ((CO_) + 3) + 255) / 256, 256, 0, stream>>>(           \
        NN, wsw + crpO[(l)], wsw + cnidO[(l)], yb, posin,                      \
        (float*)(wsw + xnO[(l)]), (float*)(wsw + pnO[(l)]));                   \
} while (0)

    LVLC(1, 15, 20);
    LVLC(2, 23, 28);
    LVLC(3, 31, 36);
    LVLC(4, 39, 44);
#undef LVLC

    fc_k<<<1, 128, 0, stream>>>((const float*)(wsw + xnO[4]),
                                (const float*)d_in[52], (const float*)d_in[53],
                                (const float*)(wsw + sqO), (float*)d_out);
}

// Round 11
// 478.689 us; speedup vs baseline: 1.0989x; 1.0989x over previous
//
#include <hip/hip_runtime.h>
#include <math.h>

// ---------------------------------------------------------------------------
// Net_37512244363273: 5-level edge-conditioned graph conv + voxel pooling + FC
// Round 11: conv0b (78 us) died on 7 serial LDS atomics/record with heavy
// same-address contention on 128 blocks. Replaced by a 512-bucket partition
// (dst>>7, ~2048 records/bucket) + conv0c: one kernel per bucket that builds
// an in-LDS CSR of record indices (2 low-contention LDS atomics/record) and
// then accumulates per-node sums in REGISTERS (zero accumulation atomics),
// 512 blocks. part0 keeps the fused h/tanh + level-0 h-stats (computed once).
// Segs 1-9 keep the XCD-bucketed atomic CSR build.
// Output: 80 log_softmax + closs = 81 floats.
// ---------------------------------------------------------------------------

#define NBUCK 8
#define TILES0 256                 // 1048576 / 4096
#define NB0    512                 // seg0 buckets (dst>>7, 128 nodes each)
#define IDXCAP 3072                // per-bucket index capacity (mean 2048, 22 sigma)

// ---- segment descriptor for CSR builds (segs 1-9: edge 1-4 + cluster 0-4) --
struct SegArgs {
    const int* idx[10];
    int*       cnt[10];
    int*       rp [10];
    int*       out[10];
    int        n  [10];
    int        nb [10];
    int        shift[10];
    int        tstart[11];
};

struct ScanAux {
    int* tilesum;
    int* tileoff;
    int  sstart[11];
    int  T;
};

// XCD-bucketed histogram (per-element global atomics; small segs only).
__global__ __launch_bounds__(256) void hist_all_k(SegArgs a) {
    int B = blockIdx.x;
    int bucket = B % NBUCK;
    int T = B / NBUCK;
    int s = 0;
    while (s < 9 && T >= a.tstart[s + 1]) s++;
    int i = (T - a.tstart[s]) * 256 + threadIdx.x;
    if (i >= a.n[s]) return;
    int d = a.idx[s][i];
    if ((d >> a.shift[s]) != bucket) return;
    atomicAdd(&a.cnt[s][d], 1);
}

// 3-phase hierarchical scan over segs 1-9 cnt arrays.
__global__ __launch_bounds__(256) void scanA_k(SegArgs a, ScanAux x) {
    int b = blockIdx.x;
    int s = 0;
    while (s < 9 && b >= x.sstart[s + 1]) s++;
    int tloc = b - x.sstart[s];
    int nb = a.nb[s];
    const int* cnt = a.cnt[s];
    int i0 = tloc * 4096 + threadIdx.x * 16;
    int sum = 0;
    #pragma unroll
    for (int k = 0; k < 16; k++) {
        int i = i0 + k;
        if (i < nb) sum += cnt[i];
    }
    #pragma unroll
    for (int o = 32; o; o >>= 1) sum += __shfl_down(sum, o);
    __shared__ int red[4];
    if ((threadIdx.x & 63) == 0) red[threadIdx.x >> 6] = sum;
    __syncthreads();
    if (threadIdx.x == 0)
        x.tilesum[b] = red[0] + red[1] + red[2] + red[3];
}

__global__ __launch_bounds__(64) void scanB_k(SegArgs a, ScanAux x) {
    int lane = threadIdx.x;
    int orig = (lane < x.T) ? x.tilesum[lane] : 0;
    int val = orig;
    #pragma unroll
    for (int d = 1; d < 64; d <<= 1) {
        int v = __shfl_up(val, d);
        if (lane >= d) val += v;
    }
    int excl = val - orig;
    int s = 0;
    while (s < 9 && lane >= x.sstart[s + 1]) s++;
    int segExcl = __shfl(excl, x.sstart[s]);
    if (lane < x.T) {
        x.tileoff[lane] = excl - segExcl;
        if (lane == x.sstart[s + 1] - 1)
            a.rp[s][a.nb[s]] = val - segExcl;
    }
}

__global__ __launch_bounds__(256) void scanC_k(SegArgs a, ScanAux x) {
    int b = blockIdx.x;
    int s = 0;
    while (s < 9 && b >= x.sstart[s + 1]) s++;
    int tloc = b - x.sstart[s];
    int nb = a.nb[s];
    const int* cnt = a.cnt[s];
    int* rp = a.rp[s];
    int i0 = tloc * 4096 + threadIdx.x * 16;
    int v[16];
    int sum = 0;
    #pragma unroll
    for (int k = 0; k < 16; k++) {
        int i = i0 + k;
        v[k] = (i < nb) ? cnt[i] : 0;
        sum += v[k];
    }
    __shared__ int sc[256];
    int acc = sum;
    sc[threadIdx.x] = acc;
    __syncthreads();
    for (int d = 1; d < 256; d <<= 1) {
        int t2 = (threadIdx.x >= d) ? sc[threadIdx.x - d] : 0;
        __syncthreads();
        acc += t2;
        sc[threadIdx.x] = acc;
        __syncthreads();
    }
    int running = x.tileoff[b] + (acc - sum);
    #pragma unroll
    for (int k = 0; k < 16; k++) {
        int i = i0 + k;
        if (i < nb) rp[i] = running;
        running += v[k];
    }
}

// XCD-bucketed countdown-scatter (small segs only).
__global__ __launch_bounds__(256) void scatter_all_k(SegArgs a) {
    int B = blockIdx.x;
    int bucket = B % NBUCK;
    int T = B / NBUCK;
    int s = 0;
    while (s < 9 && T >= a.tstart[s + 1]) s++;
    int i = (T - a.tstart[s]) * 256 + threadIdx.x;
    if (i >= a.n[s]) return;
    int d = a.idx[s][i];
    if ((d >> a.shift[s]) != bucket) return;
    int p = atomicSub(&a.cnt[s][d], 1) - 1;
    a.out[s][a.rp[s][d] + p] = i;
}

// ---------------------------------------------------------------------------
// Seg-0 pipeline: deterministic 512-bucket partition (fused h + L0 stats),
// then fused per-bucket in-LDS CSR + register accumulation conv.
// ---------------------------------------------------------------------------
__global__ __launch_bounds__(256) void cnt0_k(
    const int* __restrict__ dst, int* __restrict__ M)
{
    __shared__ int h[NB0];
    int t = threadIdx.x;
    for (int u = t; u < NB0; u += 256) h[u] = 0;
    __syncthreads();
    int base = blockIdx.x * 4096 + t;
    #pragma unroll
    for (int it = 0; it < 16; it++)
        atomicAdd(&h[dst[base + it * 256] >> 7], 1);      // LDS
    __syncthreads();
    for (int u = t; u < NB0; u += 256) M[blockIdx.x * NB0 + u] = h[u];
}

// per-bucket exclusive scan over the 256 tiles.
__global__ __launch_bounds__(256) void colscan_k(
    const int* __restrict__ M, int* __restrict__ M2, int* __restrict__ colTotal)
{
    int b = blockIdx.x, t = threadIdx.x;
    int v = M[t * NB0 + b];
    __shared__ int sc[256];
    sc[t] = v;
    __syncthreads();
    for (int d = 1; d < 256; d <<= 1) {
        int u = (t >= d) ? sc[t - d] : 0;
        __syncthreads();
        sc[t] += u;
        __syncthreads();
    }
    M2[t * NB0 + b] = sc[t] - v;
    if (t == 255) colTotal[b] = sc[255];
}

__global__ __launch_bounds__(512) void bktscan_k(
    const int* __restrict__ colTotal, int* __restrict__ bucketStart)
{
    int t = threadIdx.x;
    int v = colTotal[t];
    __shared__ int sc[NB0];
    sc[t] = v;
    __syncthreads();
    for (int d = 1; d < NB0; d <<= 1) {
        int u = (t >= d) ? sc[t - d] : 0;
        __syncthreads();
        sc[t] += u;
        __syncthreads();
    }
    bucketStart[t] = sc[t] - v;
    if (t == NB0 - 1) bucketStart[NB0] = sc[NB0 - 1];
}

// partition + fused h/tanh + level-0 h-stats. Record (2 x float4):
//   A = (x_src, h0*x, h1*x, h2*x), B = (h3*x, h4*x, 0, 0); key separate.
__global__ __launch_bounds__(256) void part0_k(
    const int* __restrict__ src, const int* __restrict__ dst,
    const float* __restrict__ ea, const float* __restrict__ x0,
    const int* __restrict__ M2, const int* __restrict__ bucketStart,
    int* __restrict__ keys, float4* __restrict__ pay2,
    const float* __restrict__ w1, const float* __restrict__ b1,
    float* __restrict__ H0)
{
    __shared__ int cur[NB0];
    __shared__ float w1s[15], b1s[5];
    __shared__ float red[4][20];
    int t = threadIdx.x;
    for (int u = t; u < NB0; u += 256)
        cur[u] = bucketStart[u] + M2[blockIdx.x * NB0 + u];
    if (t < 15) w1s[t] = w1[t];
    if (t >= 32 && t < 37) b1s[t - 32] = b1[t - 32];
    __syncthreads();

    float acc[20];
    #pragma unroll
    for (int i = 0; i < 20; i++) acc[i] = 0.f;

    int base = blockIdx.x * 4096 + t;
    #pragma unroll 4
    for (int it = 0; it < 16; it++) {
        int i = base + it * 256;
        int d = dst[i];
        float e0 = ea[i * 3], e1 = ea[i * 3 + 1], e2 = ea[i * 3 + 2];
        float h[5];
        #pragma unroll
        for (int k = 0; k < 5; k++)
            h[k] = tanhf(e0 * w1s[k] + e1 * w1s[5 + k] + e2 * w1s[10 + k] + b1s[k]);
        int p = 5;
        #pragma unroll
        for (int k = 0; k < 5; k++) {
            acc[k] += h[k];
            #pragma unroll
            for (int k2 = k; k2 < 5; k2++) acc[p++] += h[k] * h[k2];
        }
        float xv = x0[src[i]];
        int ps = atomicAdd(&cur[d >> 7], 1);              // LDS
        keys[ps] = d;
        pay2[2 * ps]     = make_float4(xv, h[0] * xv, h[1] * xv, h[2] * xv);
        pay2[2 * ps + 1] = make_float4(h[3] * xv, h[4] * xv, 0.f, 0.f);
    }

    // level-0 h-stat reduction: wave shfl -> LDS -> 20 atomics per block
    int wid = t >> 6, lane = t & 63;
    #pragma unroll
    for (int v = 0; v < 20; v++) {
        float s = acc[v];
        #pragma unroll
        for (int o = 32; o; o >>= 1) s += __shfl_down(s, o);
        if (lane == 0) red[wid][v] = s;
    }
    __syncthreads();
    if (t < 20)
        atomicAdd(&H0[t], red[0][t] + red[1][t] + red[2][t] + red[3][t]);
}

// conv0c: one block per 128-node bucket. Phase 1: LDS 128-bin histogram
// (1 LDS atomic/record). Phase 2: LDS scan + scatter record indices into
// in-LDS CSR (1 LDS atomic/record, low contention). Phase 3: 128 threads
// each walk their node's contiguous slice, accumulate 6 sums in REGISTERS,
// finalize y. Zero accumulation atomics.
__global__ __launch_bounds__(256) void conv0c_k(
    const int* __restrict__ keys, const float4* __restrict__ pay2,
    const int* __restrict__ bucketStart,
    const float* __restrict__ w2, const float* __restrict__ b2,
    const float* __restrict__ root, const float* __restrict__ bias,
    const float* __restrict__ x, float* __restrict__ y)
{
    __shared__ float w2s[60], b2s[12], roots[12], biass[12];
    __shared__ int hist[128], st[128], cur[128];
    __shared__ int idxL[IDXCAP];
    int t = threadIdx.x;
    if (t < 60) w2s[t] = w2[t];
    else if (t >= 64  && t < 76)  b2s[t - 64]    = b2[t - 64];
    else if (t >= 128 && t < 140) roots[t - 128] = root[t - 128];
    else if (t >= 192 && t < 204) biass[t - 192] = bias[t - 192];
    if (t < 128) hist[t] = 0;
    __syncthreads();

    int b = blockIdx.x;
    int lo = bucketStart[b], hi = bucketStart[b + 1];
    int bin0 = b << 7;
    for (int j = lo + t; j < hi; j += 256)
        atomicAdd(&hist[keys[j] - bin0], 1);              // LDS
    __syncthreads();
    if (t < 128) st[t] = hist[t];
    __syncthreads();
    for (int d = 1; d < 128; d <<= 1) {
        int u = (t < 128 && t >= d) ? st[t - d] : 0;
        __syncthreads();
        if (t < 128) st[t] += u;
        __syncthreads();
    }
    if (t < 128) cur[t] = st[t] - hist[t];                // exclusive
    __syncthreads();
    for (int j = lo + t; j < hi; j += 256) {
        int rel = keys[j] - bin0;
        int p = atomicAdd(&cur[rel], 1);                  // LDS
        idxL[p] = j;
    }
    __syncthreads();

    if (t < 128) {
        int v = bin0 + t;
        int deg = hist[t];
        int s0 = st[t] - deg;
        float S0 = 0.f, S1 = 0.f, S2 = 0.f, S3 = 0.f, S4 = 0.f, S5 = 0.f;
        for (int jj = s0; jj < s0 + deg; jj++) {
            int j = idxL[jj];
            float4 A = pay2[2 * j], B = pay2[2 * j + 1];
            S0 += A.x; S1 += A.y; S2 += A.z; S3 += A.w;
            S4 += B.x; S5 += B.y;
        }
        float inv = 1.f / fmaxf((float)deg, 1.f);
        float xv = x[v];
        #pragma unroll
        for (int o = 0; o < 12; o++) {
            float msg = b2s[o] * S0 + w2s[o] * S1 + w2s[12 + o] * S2 +
                        w2s[24 + o] * S3 + w2s[36 + o] * S4 + w2s[48 + o] * S5;
            y[v * 12 + o] = msg * inv + xv * roots[o] + biass[o];
        }
    }
}

// ---------------------------------------------------------------------------
// hstats (levels 1-4 only) / wstats: closs via h-statistics.
// ---------------------------------------------------------------------------
struct HArgs {
    const float* eattr[5];
    const float* w1[5];
    const float* b1[5];
    float*       H;
    int          E[5];
    int          bstart[6];
};

__global__ __launch_bounds__(256) void hstats_k(HArgs a) {
    const int K = 32;
    int b = blockIdx.x, l = 0;
    while (l < 4 && b >= a.bstart[l + 1]) l++;
    int bloc = b - a.bstart[l];
    const float* ea = a.eattr[l];
    float w1r[15], b1r[5];
    #pragma unroll
    for (int i = 0; i < 15; i++) w1r[i] = a.w1[l][i];
    #pragma unroll
    for (int i = 0; i < 5; i++)  b1r[i] = a.b1[l][i];
    float acc[20];
    #pragma unroll
    for (int i = 0; i < 20; i++) acc[i] = 0.f;
    int base = bloc * 256 * K + threadIdx.x;
    for (int it = 0; it < K; it++) {
        int e = base + it * 256;
        if (e < a.E[l]) {
            float e0 = ea[e * 3], e1 = ea[e * 3 + 1], e2 = ea[e * 3 + 2];
            float h[5];
            #pragma unroll
            for (int k = 0; k < 5; k++)
                h[k] = tanhf(e0 * w1r[k] + e1 * w1r[5 + k] + e2 * w1r[10 + k] + b1r[k]);
            int p = 5;
            #pragma unroll
            for (int k = 0; k < 5; k++) {
                acc[k] += h[k];
                #pragma unroll
                for (int k2 = k; k2 < 5; k2++) acc[p++] += h[k] * h[k2];
            }
        }
    }
    __shared__ float red[4][20];
    int wid = threadIdx.x >> 6, lane = threadIdx.x & 63;
    #pragma unroll
    for (int v = 0; v < 20; v++) {
        float s = acc[v];
        #pragma unroll
        for (int off = 32; off; off >>= 1) s += __shfl_down(s, off);
        if (lane == 0) red[wid][v] = s;
    }
    __syncthreads();
    if (threadIdx.x < 20) {
        float s = red[0][threadIdx.x] + red[1][threadIdx.x] +
                  red[2][threadIdx.x] + red[3][threadIdx.x];
        atomicAdd(&a.H[l * 20 + threadIdx.x], s);
    }
}

struct WArgs {
    const float* w2[5];
    const float* b2[5];
    const float* H;
    float*       sq;
    int          cico[5];
    int          E[5];
};

__global__ __launch_bounds__(64) void wstats_k(WArgs a) {
    int l = blockIdx.x;
    const float* w2 = a.w2[l];
    const float* b2 = a.b2[l];
    int cico = a.cico[l];
    float d[21];
    #pragma unroll
    for (int i = 0; i < 21; i++) d[i] = 0.f;
    for (int u = threadIdx.x; u < cico; u += 64) {
        float b = b2[u];
        float w[5];
        #pragma unroll
        for (int k = 0; k < 5; k++) w[k] = w2[k * cico + u];
        int p = 0;
        #pragma unroll
        for (int k = 0; k < 5; k++) {
            #pragma unroll
            for (int k2 = k; k2 < 5; k2++) d[p++] += w[k] * w[k2];
        }
        #pragma unroll
        for (int k = 0; k < 5; k++) d[15 + k] += b * w[k];
        d[20] += b * b;
    }
    #pragma unroll
    for (int i = 0; i < 21; i++) {
        #pragma unroll
        for (int off = 32; off; off >>= 1) d[i] += __shfl_down(d[i], off);
    }
    if (threadIdx.x == 0) {
        const float* H1 = a.H + l * 20;
        const float* H2 = H1 + 5;
        float sq = (float)a.E[l] * d[20];
        #pragma unroll
        for (int k = 0; k < 5; k++) sq += 2.f * d[15 + k] * H1[k];
        int p = 0;
        #pragma unroll
        for (int k = 0; k < 5; k++) {
            #pragma unroll
            for (int k2 = k; k2 < 5; k2++) {
                sq += ((k == k2) ? 1.f : 2.f) * d[p] * H2[p];
                p++;
            }
        }
        a.sq[l] = sq;
    }
}

// ---------------------------------------------------------------------------
// coop_conv_k (L1-L4): one block per node (unchanged).
// ---------------------------------------------------------------------------
template<int CI, int CO>
__global__ __launch_bounds__(256) void coop_conv_k(
    const int* __restrict__ rp, const int* __restrict__ eid,
    const int* __restrict__ src, const float* __restrict__ eattr,
    const float* __restrict__ w1, const float* __restrict__ b1,
    const float* __restrict__ w2, const float* __restrict__ b2,
    const float* __restrict__ root, const float* __restrict__ bias,
    const float* __restrict__ x, float* __restrict__ y)
{
    constexpr int CH   = 48;
    constexpr int CICO = CI * CO;
    static_assert(6 * CI <= 256, "phase-A lanes");
    __shared__ float w1s[20];
    __shared__ int   eb[CH], svb[CH];
    __shared__ float hb[CH * 6];
    __shared__ float xs[CH * CI];
    __shared__ float S[6 * CI];

    int t = threadIdx.x;
    int v = blockIdx.x;
    if (t < 20) w1s[t] = (t < 15) ? w1[t] : b1[t - 15];
    int r0 = rp[v], r1 = rp[v + 1];
    int d  = r1 - r0;
    float acc = 0.f;

    for (int c0 = r0; c0 < r1; c0 += CH) {
        int cn = min(CH, r1 - c0);
        if (t < cn) {
            int e = eid[c0 + t];
            eb[t]  = e;
            svb[t] = src[e];
            hb[t * 6] = 1.f;
        }
        __syncthreads();
        if (t < cn * 5) {
            int j = t / 5, k = t % 5;
            int e = eb[j];
            float e0 = eattr[e * 3], e1 = eattr[e * 3 + 1], e2 = eattr[e * 3 + 2];
            hb[j * 6 + 1 + k] =
                tanhf(e0 * w1s[k] + e1 * w1s[5 + k] + e2 * w1s[10 + k] + w1s[15 + k]);
        }
        for (int u = t; u < cn * CI; u += 256)
            xs[u] = x[(size_t)svb[u / CI] * CI + (u % CI)];
        __syncthreads();
        if (t < 6 * CI) {
            int i = t / 6, k6 = t % 6;
            for (int j = 0; j < cn; j++)
                acc += hb[j * 6 + k6] * xs[j * CI + i];
        }
        __syncthreads();
    }

    if (t < 6 * CI) S[t] = acc;
    __syncthreads();

    if (t < CO) {
        float m = 0.f;
        for (int i = 0; i < CI; i++) {
            m += b2[i * CO + t] * S[i * 6];
            #pragma unroll
            for (int k = 0; k < 5; k++)
                m += w2[k * CICO + i * CO + t] * S[i * 6 + 1 + k];
        }
        m /= fmaxf((float)d, 1.f);
        for (int i = 0; i < CI; i++)
            m += x[(size_t)v * CI + i] * root[i * CO + t];
        y[(size_t)v * CO + t] = m + bias[t];
    }
}

// ---------------------------------------------------------------------------
// pool_k (unchanged).
// ---------------------------------------------------------------------------
template<int CO>
__global__ __launch_bounds__(256) void pool_k(
    int NN,
    const int* __restrict__ crp, const int* __restrict__ cnid,
    const float* __restrict__ y, const float* __restrict__ pos,
    float* __restrict__ xn, float* __restrict__ pn)
{
    int t = blockIdx.x * 256 + threadIdx.x;
    if (t >= NN * (CO + 3)) return;
    int c = t / (CO + 3), o = t % (CO + 3);
    int r0 = crp[c], r1 = crp[c + 1];
    int d = r1 - r0;
    if (o < CO) {
        float m = -INFINITY;
        for (int j = r0; j < r1; j++)
            m = fmaxf(m, y[(size_t)cnid[j] * CO + o]);
        if (d == 0 || !isfinite(m)) m = 0.f;
        xn[c * (CO + 3) + o] = m;
    } else {
        int k = o - CO;
        float sum = 0.f;
        for (int j = r0; j < r1; j++)
            sum += pos[cnid[j] * 3 + k];
        float pm = sum / fmaxf((float)d, 1.f);
        xn[c * (CO + 3) + CO + k] = pm;
        pn[c * 3 + k] = pm;
    }
}

// ---------------------------------------------------------------------------
// fc_k (unchanged).
// ---------------------------------------------------------------------------
__global__ __launch_bounds__(128) void fc_k(
    const float* __restrict__ x5,
    const float* __restrict__ fc_w, const float* __restrict__ fc_b,
    const float* __restrict__ sq, float* __restrict__ out)
{
    __shared__ float feat[8 * 376];
    __shared__ float logit[80];
    __shared__ float roff[8];
    for (int t = threadIdx.x; t < 8 * 376; t += 128) feat[t] = x5[t];
    __syncthreads();
    int t = threadIdx.x;
    if (t < 80) {
        int b = t / 10, j = t % 10;
        float acc = fc_b[j];
        for (int k = 0; k < 376; k++) acc += feat[b * 376 + k] * fc_w[k * 10 + j];
        logit[t] = acc;
    }
    __syncthreads();
    if (t < 8) {
        float m = -1e30f;
        for (int j = 0; j < 10; j++) m = fmaxf(m, logit[t * 10 + j]);
        float ssum = 0.f;
        for (int j = 0; j < 10; j++) ssum += expf(logit[t * 10 + j] - m);
        roff[t] = m + logf(ssum);
    }
    __syncthreads();
    if (t < 80) out[t] = logit[t] - roff[t / 10];
    if (t == 0) {
        float closs = 0.f;
        closs += sq[0] * (1.0f / 12582912.0f);
        closs += sq[1] * (1.0f / 78643200.0f);
        closs += sq[2] * (1.0f / 42205184.0f);
        closs += sq[3] * (1.0f / 18284544.0f);
        closs += sq[4] * (1.0f / 7028736.0f);
        out[80] = closs;
    }
}

// ---------------------------------------------------------------------------

extern "C" void kernel_launch(void* const* d_in, const int* in_sizes, int n_in,
                              void* d_out, int out_size, void* d_ws, size_t ws_size,
                              hipStream_t stream)
{
    static const int NSa[6] = {65536, 16384, 4096, 1024, 256, 64};
    static const int ESa[5] = {1048576, 262144, 65536, 16384, 4096};
    static const int COa[5] = {12, 20, 28, 36, 44};
    static const int CIa[5] = {1, 15, 23, 31, 39};

    const float* x0   = (const float*)d_in[0];
    const float* pos0 = (const float*)d_in[1];

    // ---- workspace layout (words), ~46 MB total ----
    int* wsw = (int*)d_ws;
    size_t off = 0;
    auto alw = [&](size_t n) -> size_t {
        size_t p = off; off += (n + 63) & ~(size_t)63; return p;
    };
    size_t degO[5], cdegO[5];
    for (int l = 1; l < 5; l++) degO[l]  = alw(NSa[l]);
    for (int l = 0; l < 5; l++) cdegO[l] = alw(NSa[l + 1]);
    size_t HO = alw(100);
    size_t zeroWords = off;                               // zero-init to here
    size_t rpO[5], crpO[5], eidO[5], cnidO[5];
    for (int l = 1; l < 5; l++) rpO[l]  = alw(NSa[l] + 1);
    for (int l = 0; l < 5; l++) crpO[l] = alw(NSa[l + 1] + 1);
    for (int l = 1; l < 5; l++) eidO[l] = alw(ESa[l]);
    for (int l = 0; l < 5; l++) cnidO[l] = alw(NSa[l]);
    size_t tsO  = alw(64);
    size_t toO  = alw(64);
    size_t MO   = alw((size_t)TILES0 * NB0);
    size_t M2O  = alw((size_t)TILES0 * NB0);
    size_t ctO  = alw(NB0);
    size_t bsO  = alw(NB0 + 1);
    size_t keysO = alw((size_t)ESa[0]);
    size_t payO = alw((size_t)ESa[0] * 8);                // 32B records
    size_t yO   = alw((size_t)65536 * 12);
    size_t sqO  = alw(8);
    size_t xnO[5], pnO[5];
    for (int l = 0; l < 5; l++) xnO[l] = alw((size_t)NSa[l + 1] * (COa[l] + 3));
    for (int l = 0; l < 5; l++) pnO[l] = alw((size_t)NSa[l + 1] * 3);

    hipMemsetAsync(d_ws, 0, zeroWords * 4, stream);

    // ---- segs 1-9 descriptor (edge segs 1-4 + cluster segs 0-4) ----
    SegArgs sa{};
    int nseg = 0;
    for (int l = 1; l < 5; l++) {
        sa.idx[nseg] = (const int*)d_in[3 + 10 * l];
        sa.cnt[nseg] = wsw + degO[l];
        sa.rp [nseg] = wsw + rpO[l];
        sa.out[nseg] = wsw + eidO[l];
        sa.n  [nseg] = ESa[l];
        sa.nb [nseg] = NSa[l];
        nseg++;
    }
    for (int l = 0; l < 5; l++) {
        sa.idx[nseg] = (const int*)d_in[5 + 10 * l];
        sa.cnt[nseg] = wsw + cdegO[l];
        sa.rp [nseg] = wsw + crpO[l];
        sa.out[nseg] = wsw + cnidO[l];
        sa.n  [nseg] = NSa[l];
        sa.nb [nseg] = NSa[l + 1];
        nseg++;
    }
    ScanAux sx{};
    int tiles = 0, btiles = 0;
    for (int s = 0; s < nseg; s++) {
        int lg = 31 - __builtin_clz(sa.nb[s]);
        sa.shift[s] = lg - 3;
        sa.tstart[s] = tiles;
        tiles += (sa.n[s] + 255) / 256;
        sx.sstart[s] = btiles;
        btiles += (sa.nb[s] + 4095) / 4096;
    }
    for (int s = nseg; s <= 10; s++) {
        sa.tstart[s] = tiles;
        sx.sstart[s] = btiles;
        if (s < 10) {
            sa.idx[s] = sa.idx[nseg - 1]; sa.cnt[s] = sa.cnt[nseg - 1];
            sa.rp[s] = sa.rp[nseg - 1];   sa.out[s] = sa.out[nseg - 1];
            sa.n[s] = 0; sa.nb[s] = 8; sa.shift[s] = 0;
        }
    }
    sx.T = btiles;
    sx.tilesum = wsw + tsO;
    sx.tileoff = wsw + toO;

    int*    keys = wsw + keysO;
    float4* pay2 = (float4*)(wsw + payO);
    float*  Hp   = (float*)(wsw + HO);

    // ---- seg0 deterministic radix build + fused h/stats ----
    cnt0_k   <<<TILES0, 256, 0, stream>>>((const int*)d_in[3], wsw + MO);
    colscan_k<<<NB0, 256, 0, stream>>>(wsw + MO, wsw + M2O, wsw + ctO);
    bktscan_k<<<1, NB0, 0, stream>>>(wsw + ctO, wsw + bsO);
    part0_k  <<<TILES0, 256, 0, stream>>>(
        (const int*)d_in[2], (const int*)d_in[3], (const float*)d_in[4],
        x0, wsw + M2O, wsw + bsO, keys, pay2,
        (const float*)d_in[6], (const float*)d_in[7], Hp);

    // ---- segs 1-9 atomic build ----
    hist_all_k   <<<tiles * NBUCK, 256, 0, stream>>>(sa);
    scanA_k      <<<btiles, 256, 0, stream>>>(sa, sx);
    scanB_k      <<<1, 64, 0, stream>>>(sa, sx);
    scanC_k      <<<btiles, 256, 0, stream>>>(sa, sx);
    scatter_all_k<<<tiles * NBUCK, 256, 0, stream>>>(sa);

    // ---- closs statistics: hstats for levels 1-4 only ----
    HArgs ha{};
    int bs = 0;
    ha.bstart[0] = 0;
    ha.eattr[0] = (const float*)d_in[4];
    ha.w1[0] = (const float*)d_in[6];
    ha.b1[0] = (const float*)d_in[7];
    ha.E[0] = 0;
    for (int l = 1; l < 5; l++) {
        ha.eattr[l] = (const float*)d_in[4 + 10 * l];
        ha.w1[l]    = (const float*)d_in[6 + 10 * l];
        ha.b1[l]    = (const float*)d_in[7 + 10 * l];
        ha.E[l]     = ESa[l];
        ha.bstart[l] = bs;
        bs += (ESa[l] + 256 * 32 - 1) / (256 * 32);
    }
    ha.bstart[5] = bs;
    ha.H = Hp;
    hstats_k<<<bs, 256, 0, stream>>>(ha);

    WArgs wa{};
    for (int l = 0; l < 5; l++) {
        wa.w2[l]   = (const float*)d_in[8 + 10 * l];
        wa.b2[l]   = (const float*)d_in[9 + 10 * l];
        wa.cico[l] = CIa[l] * COa[l];
        wa.E[l]    = ESa[l];
    }
    wa.H  = Hp;
    wa.sq = (float*)(wsw + sqO);
    wstats_k<<<5, 64, 0, stream>>>(wa);

    float* yb = (float*)(wsw + yO);

    // ---- level 0: fused in-LDS CSR + register accumulation conv ----
    conv0c_k<<<NB0, 256, 0, stream>>>(
        keys, pay2, wsw + bsO,
        (const float*)d_in[8], (const float*)d_in[9],
        (const float*)d_in[10], (const float*)d_in[11], x0, yb);
    pool_k<12><<<(NSa[1] * 15 + 255) / 256, 256, 0, stream>>>(
        NSa[1], wsw + crpO[0], wsw + cnidO[0], yb, pos0,
        (float*)(wsw + xnO[0]), (float*)(wsw + pnO[0]));

    // ---- levels 1-4 ----
#define LVLC(l, CI_, CO_) do {                                                 \
    const float* xin   = (const float*)(wsw + xnO[(l) - 1]);                   \
    const float* posin = (const float*)(wsw + pnO[(l) - 1]);                   \
    int N = NSa[(l)], NN = NSa[(l) + 1];                                       \
    coop_conv_k<CI_, CO_><<<N, 256, 0, stream>>>(                              \
        wsw + rpO[(l)], wsw + eidO[(l)],                                       \
        (const int*)d_in[2 + 10 * (l)], (const float*)d_in[4 + 10 * (l)],      \
        (const float*)d_in[6 + 10 * (l)], (const float*)d_in[7 + 10 * (l)],    \
        (const float*)d_in[8 + 10 * (l)], (const float*)d_in[9 + 10 * (l)],    \
        (const float*)d_in[10 + 10 * (l)], (const float*)d_in[11 + 10 * (l)],  \
        xin, yb);                                                              \
    pool_k<CO_><<<(NN * ((CO_) + 3) + 255) / 256, 256, 0, stream>>>(           \
        NN, wsw + crpO[(l)], wsw + cnidO[(l)], yb, posin,                      \
        (float*)(wsw + xnO[(l)]), (float*)(wsw + pnO[(l)]));                   \
} while (0)

    LVLC(1, 15, 20);
    LVLC(2, 23, 28);
    LVLC(3, 31, 36);
    LVLC(4, 39, 44);
#undef LVLC

    fc_k<<<1, 128, 0, stream>>>((const float*)(wsw + xnO[4]),
                                (const float*)d_in[52], (const float*)d_in[53],
                                (const float*)(wsw + sqO), (float*)d_out);
}